// Round 21
// baseline (109.559 us; speedup 1.0000x reference)
//
#include <hip/hip_runtime.h>
#include <hip/hip_bf16.h>
#include <stdint.h>

#define B_ 2
#define S_ 2048
#define D_ 1024
#define H_ 16
#define HD_ 64
#define M_ (B_*S_)        // 4096 rows
#define NQKV_ (H_*3*HD_)  // 3072

typedef __attribute__((ext_vector_type(8))) short short8;
typedef __attribute__((ext_vector_type(4))) float f32x4;
typedef unsigned short u16;
typedef unsigned int u32;

__device__ __forceinline__ u16 f2b(float f){
  u32 u = __float_as_uint(f);
  u32 r = (u + 0x7FFFu + ((u >> 16) & 1u)) >> 16;   // RNE f32->bf16
  return (u16)r;
}

__device__ __forceinline__ float exp2v(float x){
  float r; asm("v_exp_f32 %0, %1" : "=v"(r) : "v"(x)); return r;
}

__device__ __forceinline__ void gl_lds16(const void* g, void* l){
  __builtin_amdgcn_global_load_lds(
      (const __attribute__((address_space(1))) void*)g,
      (__attribute__((address_space(3))) void*)l, 16, 0, 0);
}

// ===== prep: LN (blocks 0..4095) + wqkv tconv + wout tconv =====
__global__ __launch_bounds__(256) void prep_kernel(
    const float* __restrict__ x, const float* __restrict__ gam,
    const float* __restrict__ bet, u16* __restrict__ xn,
    const float* __restrict__ wqkv, u16* __restrict__ wqkvT,
    const float* __restrict__ wout, u16* __restrict__ woutT){
  int bid = blockIdx.x;
  __shared__ float tile[64][65];
  if(bid < M_){
    int row = bid;
    const float4* xr = (const float4*)(x + (size_t)row * D_);
    float4 v = xr[threadIdx.x];
    float s = v.x + v.y + v.z + v.w;
    float q = v.x*v.x + v.y*v.y + v.z*v.z + v.w*v.w;
    #pragma unroll
    for(int o = 32; o > 0; o >>= 1){ s += __shfl_down(s, o); q += __shfl_down(q, o); }
    float* red = &tile[0][0];
    int w = threadIdx.x >> 6, lane = threadIdx.x & 63;
    if(lane == 0){ red[w] = s; red[4+w] = q; }
    __syncthreads();
    float st = red[0]+red[1]+red[2]+red[3];
    float qt = red[4]+red[5]+red[6]+red[7];
    float mu = st * (1.0f / D_);
    float inv = rsqrtf(qt * (1.0f / D_) - mu*mu + 1e-6f);
    float4 g = ((const float4*)gam)[threadIdx.x];
    float4 b = ((const float4*)bet)[threadIdx.x];
    ushort4 o4;
    o4.x = f2b((v.x-mu)*inv*g.x + b.x);
    o4.y = f2b((v.y-mu)*inv*g.y + b.y);
    o4.z = f2b((v.z-mu)*inv*g.z + b.z);
    o4.w = f2b((v.w-mu)*inv*g.w + b.w);
    ((ushort4*)(xn + (size_t)row * D_))[threadIdx.x] = o4;
    return;
  }
  const float* src; u16* dst; int C, cx, ry;
  if(bid < M_ + (NQKV_/64)*(D_/64)){
    int idx = bid - M_;
    cx = idx % (NQKV_/64); ry = idx / (NQKV_/64);
    src = wqkv; dst = wqkvT; C = NQKV_;
  } else {
    int idx = bid - M_ - (NQKV_/64)*(D_/64);
    cx = idx % (D_/64); ry = idx / (D_/64);
    src = wout; dst = woutT; C = D_;
  }
  const int R = D_;
  int tx = threadIdx.x & 63, ty = threadIdx.x >> 6;
  int r0 = ry * 64, c0 = cx * 64;
  #pragma unroll
  for(int i = 0; i < 16; i++){
    int r = ty*16 + i;
    tile[r][tx] = src[(size_t)(r0+r)*C + c0 + tx];
  }
  __syncthreads();
  #pragma unroll
  for(int i = 0; i < 16; i++){
    int r = ty*16 + i;
    dst[(size_t)(c0+r)*R + r0 + tx] = f2b(tile[tx][r]);
  }
}

// ====== QKV GEMM: 128x192 tile, 8 waves, 2 blocks/CU, single-barrier pipeline ======
// A [M][1024] x Bt [3072][1024] bf16. LDS 80KB: A dbuf 2x16K | B dbuf 2x24K.
// Waves 2M x 4N (per-wave 64x48, acc[4][3]). BK=64; 16 K-tiles.
// Epilogue: Q (x0.125*log2e) / K -> [BH][S][HD]; V -> Vt [BH][HD][S] (n0 per-head).
__global__ __launch_bounds__(512, 2) void gemm256_kernel(const u16* __restrict__ A,
    const u16* __restrict__ Bt, const float* __restrict__ bias,
    u16* __restrict__ o0, u16* __restrict__ o1, u16* __restrict__ o2t){
  constexpr int K_ = 1024;
  __shared__ __align__(16) char smem[81920];   // [0,32K) A bufs, [32K,80K) B bufs
  int tid = threadIdx.x, w = tid >> 6, lane = tid & 63;
  int ln15 = lane & 15, g = lane >> 4;
  int wm = w >> 2, wn = w & 3;
  int bid = blockIdx.y * gridDim.x + blockIdx.x;
  int nwg = gridDim.x * gridDim.y;             // 512
  int cpx = nwg >> 3;
  int swz = (bid & 7) * cpx + (bid >> 3);      // XCD-bijective (512%8==0)
  int m0 = (swz / gridDim.x) * 128, n0 = (swz % gridDim.x) * 192;

  f32x4 z = {0.f, 0.f, 0.f, 0.f};
  f32x4 acc[4][3];
  #pragma unroll
  for(int r = 0; r < 4; r++)
    #pragma unroll
    for(int c = 0; c < 3; c++) acc[r][c] = z;

  int srow = tid >> 3;                         // 0..63
  int sch = (tid & 7) ^ (srow & 7);            // pre-swizzled source chunk
  auto STAGE = [&](int buf, int kt){           // 2 A-loads + 3 B-loads per thread
    #pragma unroll
    for(int l = 0; l < 2; l++)
      gl_lds16(A + (size_t)(m0 + l*64 + srow)*K_ + kt*64 + sch*8,
               smem + buf*16384 + l*8192 + tid*16);
    #pragma unroll
    for(int l = 0; l < 3; l++)
      gl_lds16(Bt + (size_t)(n0 + l*64 + srow)*K_ + kt*64 + sch*8,
               smem + 32768 + buf*24576 + l*8192 + tid*16);
  };

  auto LDA = [&](int buf, int r, int k)->short8{
    int row = wm*64 + r*16 + ln15;
    return *(const short8*)(smem + buf*16384 + row*128 + (((k*4 + g) ^ (row & 7)) * 16));
  };
  auto LDB = [&](int buf, int c, int k)->short8{
    int row = wn*48 + c*16 + ln15;
    return *(const short8*)(smem + 32768 + buf*24576 + row*128 + (((k*4 + g) ^ (row & 7)) * 16));
  };

  constexpr int nk = K_ / 64;                  // 16 K-tiles
  STAGE(0, 0);
  int cur = 0;
  for(int t = 0; t < nk; t++){
    asm volatile("s_waitcnt vmcnt(0)" ::: "memory");   // own stage(t) loads landed
    __builtin_amdgcn_sched_barrier(0);
    __builtin_amdgcn_s_barrier();                      // all waves' t-loads landed
                                                       // + all finished compute t-1
    if(t + 1 < nk) STAGE(cur ^ 1, t + 1);              // overwrite-safe post-barrier
    short8 a[4][2], b[3][2];
    #pragma unroll
    for(int r = 0; r < 4; r++){ a[r][0] = LDA(cur, r, 0); a[r][1] = LDA(cur, r, 1); }
    #pragma unroll
    for(int c = 0; c < 3; c++){ b[c][0] = LDB(cur, c, 0); b[c][1] = LDB(cur, c, 1); }
    __builtin_amdgcn_s_setprio(1);
    #pragma unroll
    for(int r = 0; r < 4; r++)
      #pragma unroll
      for(int c = 0; c < 3; c++){
        acc[r][c] = __builtin_amdgcn_mfma_f32_16x16x32_bf16(a[r][0], b[c][0], acc[r][c], 0, 0, 0);
        acc[r][c] = __builtin_amdgcn_mfma_f32_16x16x32_bf16(a[r][1], b[c][1], acc[r][c], 0, 0, 0);
      }
    __builtin_amdgcn_s_setprio(0);
    cur ^= 1;
  }

  // ---- epilogue: Q x0.125*log2e, K -> [BH][S][HD]; V -> Vt [BH][HD][S] ----
  int h = n0 / 192;
  #pragma unroll
  for(int r = 0; r < 4; r++){
    #pragma unroll
    for(int c = 0; c < 3; c++){
      #pragma unroll
      for(int q = 0; q < 4; q++){
        int row = m0 + wm*64 + r*16 + g*4 + q;
        int rr = wn*48 + c*16 + ln15;
        float v = acc[r][c][q] + bias[h*192 + rr];
        int b2 = row >> 11, s = row & (S_ - 1);
        if(rr < 64){
          o0[((size_t)(b2*H_ + h)*S_ + s)*HD_ + rr] = f2b(v * 0.180336884f);  // 0.125*log2(e)
        } else if(rr < 128){
          o1[((size_t)(b2*H_ + h)*S_ + s)*HD_ + rr - 64] = f2b(v);
        } else {
          o2t[((size_t)(b2*H_ + h)*HD_ + rr - 128)*S_ + s] = f2b(v);          // transposed
        }
      }
    }
  }
}

// ------- GEMM2, 8-wave, SINGLE-barrier 2-phase pipeline, XCD swizzle -------
__global__ __launch_bounds__(512) void gemm_kernel(const u16* __restrict__ A,
    const u16* __restrict__ Bt, const float* __restrict__ bias,
    float* __restrict__ out, int K, int N){
  __shared__ u16 As[2][128*32];
  __shared__ u16 Bs[2][128*32];
  int tid = threadIdx.x, w = tid >> 6, lane = tid & 63;
  int ln15 = lane & 15, g = lane >> 4;
  int bid = blockIdx.y * gridDim.x + blockIdx.x;
  int nwg = gridDim.x * gridDim.y;
  int cpx = nwg >> 3;
  int swz = (bid & 7) * cpx + (bid >> 3);
  int m0 = (swz / gridDim.x) * 128, n0 = (swz % gridDim.x) * 128;
  int wm = w >> 2, wn = w & 3;
  f32x4 z = {0.f, 0.f, 0.f, 0.f};
  f32x4 acc[4][2];
  #pragma unroll
  for(int r = 0; r < 4; r++){ acc[r][0] = z; acc[r][1] = z; }
  int srow = tid >> 2, sch = (tid & 3) * 8;        // 512 thr cover 128x32 in one shot
  const u16* Ag = A + (size_t)(m0 + srow) * K + sch;
  const u16* Bg = Bt + (size_t)(n0 + srow) * K + sch;

  auto STAGE = [&](int buf, int kt){
    gl_lds16(Ag + kt, &As[buf][srow*32 + sch]);
    gl_lds16(Bg + kt, &Bs[buf][srow*32 + sch]);
  };

  int nk = K >> 5;
  STAGE(0, 0);
  int cur = 0;
  for(int t = 0; t < nk; t++){
    asm volatile("s_waitcnt vmcnt(0)" ::: "memory");   // own stage(t) pair landed
    __builtin_amdgcn_sched_barrier(0);
    __builtin_amdgcn_s_barrier();                      // all waves' t-loads landed
                                                       // + all finished compute t-1
    if(t + 1 < nk) STAGE(cur ^ 1, (t + 1) * 32);       // overwrite-safe post-barrier
    int kc = g * 8;
    int ar = wm*64 + ln15;
    int bc = wn*32 + ln15;
    short8 af[4], bfr[2];
    #pragma unroll
    for(int r = 0; r < 4; r++) af[r] = *(const short8*)&As[cur][(ar + r*16)*32 + kc];
    #pragma unroll
    for(int c = 0; c < 2; c++) bfr[c] = *(const short8*)&Bs[cur][(bc + c*16)*32 + kc];
    __builtin_amdgcn_s_setprio(1);
    #pragma unroll
    for(int r = 0; r < 4; r++)
      #pragma unroll
      for(int c = 0; c < 2; c++)
        acc[r][c] = __builtin_amdgcn_mfma_f32_16x16x32_bf16(af[r], bfr[c], acc[r][c], 0, 0, 0);
    __builtin_amdgcn_s_setprio(0);
    cur ^= 1;
  }

  #pragma unroll
  for(int r = 0; r < 4; r++){
    #pragma unroll
    for(int c = 0; c < 2; c++){
      #pragma unroll
      for(int q = 0; q < 4; q++){
        int row = m0 + wm*64 + r*16 + g*4 + q;
        int col = n0 + wn*32 + c*16 + ln15;
        out[(size_t)row * N + col] = acc[r][c][q] + bias[col];
      }
    }
  }
}

// ======================= causal flash attention =======================
// 1024 blocks: one q-strip per block, 8 waves; waves 0-3 kv-half0, 4-7
// kv-half1; shared P; deferred l; R15 big-first decode; bh->XCD grouping.
// Single-barrier pipeline; explicit sync before merge (Mg overlaps K/V).

template<int HALF>  // 0 = kv 0..31, 1 = kv 32..63
__device__ __forceinline__ void compute_tile(
    const char* KsB, const char* VsB, char* Pw, const short8* qf,
    f32x4* o, float& m_run, float& l_run, bool diag, int lane, int wr){
  constexpr int KB0 = (HALF == 1) ? 2 : 0;
  f32x4 z = {0.f, 0.f, 0.f, 0.f};
  f32x4 sf[4];
  __builtin_amdgcn_s_setprio(1);
  #pragma unroll
  for(int kb = KB0; kb < KB0 + 2; kb++){
    f32x4 acc = z;
    #pragma unroll
    for(int c = 0; c < 2; c++){
      int row = kb*16 + (lane & 15);
      int kc16 = (lane >> 4) + c*4;
      short8 kf = *(const short8*)(KsB + row*128 + ((kc16 ^ (row & 7)) * 16));
      acc = __builtin_amdgcn_mfma_f32_16x16x32_bf16(kf, qf[c], acc, 0, 0, 0);
    }
    sf[kb] = acc;
  }
  __builtin_amdgcn_s_setprio(0);
  if(diag){
    int qo = wr*16 + (lane & 15);
    #pragma unroll
    for(int kb = KB0; kb < KB0 + 2; kb++)
      #pragma unroll
      for(int r = 0; r < 4; r++){
        int kvo = kb*16 + (lane >> 4)*4 + r;
        if(kvo > qo) sf[kb][r] = -1e30f;
      }
  }
  int g = lane >> 4;
  float pmax = -1e28f;                       // floor: fully-masked rows -> p=0
  #pragma unroll
  for(int kb = KB0; kb < KB0 + 2; kb++)
    pmax = fmaxf(pmax, fmaxf(fmaxf(sf[kb][0], sf[kb][1]), fmaxf(sf[kb][2], sf[kb][3])));
  pmax = fmaxf(pmax, __shfl_xor(pmax, 16));
  pmax = fmaxf(pmax, __shfl_xor(pmax, 32));
  if(!__all(pmax <= m_run + 8.f)){           // T13 defer-max (log2 domain)
    float mn = fmaxf(m_run, pmax);
    float al = exp2v(m_run - mn);
    m_run = mn;
    l_run *= al;                             // per-lane partial (deferred reduce)
    float alr[4];
    #pragma unroll
    for(int r = 0; r < 4; r++) alr[r] = __shfl(al, g*4 + r);
    #pragma unroll
    for(int n = 0; n < 4; n++)
      #pragma unroll
      for(int r = 0; r < 4; r++) o[n][r] *= alr[r];
  }
  float p[4][4];
  float sum = 0.f;
  #pragma unroll
  for(int kb = KB0; kb < KB0 + 2; kb++){
    #pragma unroll
    for(int r = 0; r < 4; r++) p[kb][r] = exp2v(sf[kb][r] - m_run);
    sum += (p[kb][0]+p[kb][1]) + (p[kb][2]+p[kb][3]);
  }
  l_run += sum;                              // no per-tile cross-lane reduce
  int qrow = lane & 15;
  #pragma unroll
  for(int kb = KB0; kb < KB0 + 2; kb++){
    u32 lo, hi;
    asm("v_cvt_pk_bf16_f32 %0, %1, %2" : "=v"(lo) : "v"(p[kb][0]), "v"(p[kb][1]));
    asm("v_cvt_pk_bf16_f32 %0, %1, %2" : "=v"(hi) : "v"(p[kb][2]), "v"(p[kb][3]));
    uint2 pk; pk.x = lo; pk.y = hi;
    int byt = (qrow*128 + kb*32 + g*8) ^ ((qrow & 7) << 4);
    *(uint2*)(Pw + byt) = pk;
  }
  __builtin_amdgcn_s_setprio(1);
  {
    constexpr int c = HALF;
    int prow = lane & 15;
    int kb16 = ((lane >> 4) + c*4) * 16;
    short8 pa = *(const short8*)(Pw + ((prow*128 + kb16) ^ ((prow & 7) << 4)));
    #pragma unroll
    for(int n = 0; n < 4; n++){
      int vrow = n*16 + (lane & 15);
      int kc16 = (lane >> 4) + c*4;
      short8 vf = *(const short8*)(VsB + vrow*128 + ((kc16 ^ (vrow & 7)) * 16));
      o[n] = __builtin_amdgcn_mfma_f32_16x16x32_bf16(pa, vf, o[n], 0, 0, 0);
    }
  }
  __builtin_amdgcn_s_setprio(0);
}

__global__ __launch_bounds__(512) void attn_kernel(const u16* __restrict__ Q,
    const u16* __restrict__ Kb, const u16* __restrict__ Vt, u16* __restrict__ O){
  // LDS: [0,32K) K/V dbuf | [32K,40K) P (4 regions x 2KB, shared by role pairs)
  __shared__ __align__(16) char smem[40960];
  char* PsBase = smem + 32768;
  int tid = threadIdx.x, w = tid >> 6, lane = tid & 63;
  int wr = w & 3, role = w >> 2;
  // R15 big-first decode: qt descends with L; L%8 = bh&7 keeps XCD L2 grouping
  int L = blockIdx.x;
  int qt = 31 - (L >> 5);
  int bh = (L & 7) + 8 * ((L >> 3) & 3);
  const u16* Qg = Q + (size_t)bh * S_ * HD_;
  const u16* Kg = Kb + (size_t)bh * S_ * HD_;
  const u16* Vg = Vt + (size_t)bh * HD_ * S_;
  int b = bh >> 4, h = bh & 15;

  short8 qf[2];
  {
    int rq = qt*64 + wr*16 + (lane & 15);
    #pragma unroll
    for(int c = 0; c < 2; c++)
      qf[c] = *(const short8*)(Qg + (size_t)rq*HD_ + (lane >> 4)*8 + c*32);
  }
  f32x4 z = {0.f, 0.f, 0.f, 0.f};
  f32x4 o[4];
  float m_run = -1e30f, l_run = 0.f;
  #pragma unroll
  for(int i = 0; i < 4; i++) o[i] = z;
  int svrow = lane >> 3, scb = lane & 7;

  auto STAGE = [&](int buf, int kt){
    int kv0 = kt * 64;
    int rowblk = w * 8;
    int row = rowblk + svrow;
    int cbs = scb ^ (row & 7);
    gl_lds16(Kg + (size_t)(kv0 + row)*HD_ + cbs*8, smem + buf*8192 + rowblk*128);
    gl_lds16(Vg + (size_t)row*S_ + kv0 + cbs*8, smem + 16384 + buf*8192 + rowblk*128);
  };

  STAGE(0, 0);
  int cur = 0;
  char* Pw = PsBase + wr*2048;         // shared by role pair (disjoint XOR byte sets)
  for(int kt = 0; kt <= qt; kt++){
    asm volatile("s_waitcnt vmcnt(0)" ::: "memory");   // own stage(kt) pair landed
    __builtin_amdgcn_sched_barrier(0);
    __builtin_amdgcn_s_barrier();                      // all kt-loads landed + all
                                                       // finished compute kt-1
    if(kt < qt) STAGE(cur ^ 1, kt + 1);                // overwrite-safe post-barrier
    const char* KsB = (const char*)(smem + cur*8192);
    const char* VsB = (const char*)(smem + 16384 + cur*8192);
    if(role == 0) compute_tile<0>(KsB, VsB, Pw, qf, o, m_run, l_run, kt == qt, lane, wr);
    else          compute_tile<1>(KsB, VsB, Pw, qf, o, m_run, l_run, kt == qt, lane, wr);
    cur ^= 1;
  }

  // reduce deferred per-lane l once per sweep
  l_run += __shfl_xor(l_run, 16);
  l_run += __shfl_xor(l_run, 32);

  __syncthreads();   // ALL waves done with K/V LDS before Mg (overlapping) is written

  // merge half0 (role0) x half1 (role1): role1 publishes, role0 merges+writes
  float* Mg = (float*)smem + wr*1072;
  if(role == 1){
    #pragma unroll
    for(int n = 0; n < 4; n++)
      #pragma unroll
      for(int r = 0; r < 4; r++)
        Mg[((lane >> 4)*4 + r)*65 + n*16 + (lane & 15)] = o[n][r];
    if(lane < 16){ Mg[1040 + lane] = m_run; Mg[1056 + lane] = l_run; }
  }
  __syncthreads();
  if(role == 0){
    float F1[4], F2[4], den[4];
    #pragma unroll
    for(int r = 0; r < 4; r++){
      int row = (lane >> 4)*4 + r;
      float m1r = __shfl(m_run, row);
      float l1r = __shfl(l_run, row);
      float m2r = Mg[1040 + row];
      float l2r = Mg[1056 + row];
      float mm = fmaxf(m1r, m2r);
      F1[r] = exp2v(m1r - mm);
      F2[r] = exp2v(m2r - mm);
      den[r] = 1.f / (l1r*F1[r] + l2r*F2[r]);
    }
    #pragma unroll
    for(int n = 0; n < 4; n++)
      #pragma unroll
      for(int r = 0; r < 4; r++){
        int row = (lane >> 4)*4 + r;
        float o2 = Mg[row*65 + n*16 + (lane & 15)];
        float val = (o[n][r]*F1[r] + o2*F2[r]) * den[r];
        int s = qt*64 + wr*16 + row;
        int hd = n*16 + (lane & 15);
        O[(((size_t)(b*S_ + s))*H_ + h)*HD_ + hd] = f2b(val);
      }
  }
}

extern "C" void kernel_launch(void* const* d_in, const int* in_sizes, int n_in,
                              void* d_out, int out_size, void* d_ws, size_t ws_size,
                              hipStream_t stream){
  (void)in_sizes; (void)n_in; (void)out_size; (void)ws_size;
  const float* x    = (const float*)d_in[0];
  const float* gam  = (const float*)d_in[1];
  const float* bet  = (const float*)d_in[2];
  const float* wqkv = (const float*)d_in[3];
  const float* bqkv = (const float*)d_in[4];
  const float* wout = (const float*)d_in[5];
  const float* bout = (const float*)d_in[6];
  char* ws = (char*)d_ws;
  u16* xn    = (u16*)(ws);
  u16* wqkvT = (u16*)(ws + 8388608);
  u16* woutT = (u16*)(ws + 8388608 + 6291456);
  u16* Qb    = (u16*)(ws + 16777216);
  u16* Kb    = (u16*)(ws + 16777216 + 8388608);
  u16* Vt    = (u16*)(ws + 16777216 + 2*8388608);
  u16* attnb = xn;                      // xn dead after GEMM1 -> reuse
  float* out = (float*)d_out;           // f32 output

  prep_kernel<<<dim3(M_ + (NQKV_/64)*(D_/64) + (D_/64)*(D_/64)), dim3(256), 0, stream>>>(
      x, gam, bet, xn, wqkv, wqkvT, wout, woutT);
  gemm256_kernel<<<dim3(NQKV_/192, M_/128), dim3(512), 0, stream>>>(xn, wqkvT, bqkv, Qb, Kb, Vt);
  attn_kernel<<<dim3(32*B_*H_), dim3(512), 0, stream>>>(Qb, Kb, Vt, attnb);
  gemm_kernel<<<dim3(D_/128, M_/128), dim3(512), 0, stream>>>(attnb, woutT, bout, out, D_, D_);
}

// Round 22
// 104.778 us; speedup vs baseline: 1.0456x; 1.0456x over previous
//
#include <hip/hip_runtime.h>
#include <hip/hip_bf16.h>
#include <stdint.h>

#define B_ 2
#define S_ 2048
#define D_ 1024
#define H_ 16
#define HD_ 64
#define M_ (B_*S_)        // 4096 rows
#define NQKV_ (H_*3*HD_)  // 3072

typedef __attribute__((ext_vector_type(8))) short short8;
typedef __attribute__((ext_vector_type(4))) float f32x4;
typedef unsigned short u16;
typedef unsigned int u32;

__device__ __forceinline__ u16 f2b(float f){
  u32 u = __float_as_uint(f);
  u32 r = (u + 0x7FFFu + ((u >> 16) & 1u)) >> 16;   // RNE f32->bf16
  return (u16)r;
}

__device__ __forceinline__ float exp2v(float x){
  float r; asm("v_exp_f32 %0, %1" : "=v"(r) : "v"(x)); return r;
}

__device__ __forceinline__ void gl_lds16(const void* g, void* l){
  __builtin_amdgcn_global_load_lds(
      (const __attribute__((address_space(1))) void*)g,
      (__attribute__((address_space(3))) void*)l, 16, 0, 0);
}

// ===== prep: LN (blocks 0..4095) + wqkv tconv + wout tconv =====
__global__ __launch_bounds__(256) void prep_kernel(
    const float* __restrict__ x, const float* __restrict__ gam,
    const float* __restrict__ bet, u16* __restrict__ xn,
    const float* __restrict__ wqkv, u16* __restrict__ wqkvT,
    const float* __restrict__ wout, u16* __restrict__ woutT){
  int bid = blockIdx.x;
  __shared__ float tile[64][65];
  if(bid < M_){
    int row = bid;
    const float4* xr = (const float4*)(x + (size_t)row * D_);
    float4 v = xr[threadIdx.x];
    float s = v.x + v.y + v.z + v.w;
    float q = v.x*v.x + v.y*v.y + v.z*v.z + v.w*v.w;
    #pragma unroll
    for(int o = 32; o > 0; o >>= 1){ s += __shfl_down(s, o); q += __shfl_down(q, o); }
    float* red = &tile[0][0];
    int w = threadIdx.x >> 6, lane = threadIdx.x & 63;
    if(lane == 0){ red[w] = s; red[4+w] = q; }
    __syncthreads();
    float st = red[0]+red[1]+red[2]+red[3];
    float qt = red[4]+red[5]+red[6]+red[7];
    float mu = st * (1.0f / D_);
    float inv = rsqrtf(qt * (1.0f / D_) - mu*mu + 1e-6f);
    float4 g = ((const float4*)gam)[threadIdx.x];
    float4 b = ((const float4*)bet)[threadIdx.x];
    ushort4 o4;
    o4.x = f2b((v.x-mu)*inv*g.x + b.x);
    o4.y = f2b((v.y-mu)*inv*g.y + b.y);
    o4.z = f2b((v.z-mu)*inv*g.z + b.z);
    o4.w = f2b((v.w-mu)*inv*g.w + b.w);
    ((ushort4*)(xn + (size_t)row * D_))[threadIdx.x] = o4;
    return;
  }
  const float* src; u16* dst; int C, cx, ry;
  if(bid < M_ + (NQKV_/64)*(D_/64)){
    int idx = bid - M_;
    cx = idx % (NQKV_/64); ry = idx / (NQKV_/64);
    src = wqkv; dst = wqkvT; C = NQKV_;
  } else {
    int idx = bid - M_ - (NQKV_/64)*(D_/64);
    cx = idx % (D_/64); ry = idx / (D_/64);
    src = wout; dst = woutT; C = D_;
  }
  const int R = D_;
  int tx = threadIdx.x & 63, ty = threadIdx.x >> 6;
  int r0 = ry * 64, c0 = cx * 64;
  #pragma unroll
  for(int i = 0; i < 16; i++){
    int r = ty*16 + i;
    tile[r][tx] = src[(size_t)(r0+r)*C + c0 + tx];
  }
  __syncthreads();
  #pragma unroll
  for(int i = 0; i < 16; i++){
    int r = ty*16 + i;
    dst[(size_t)(c0+r)*R + r0 + tx] = f2b(tile[tx][r]);
  }
}

// ====== 256x192 8-wave 4-phase pipelined GEMM for QKV projection (R20 version) ======
__global__ __launch_bounds__(512, 1) void gemm256_kernel(const u16* __restrict__ A,
    const u16* __restrict__ Bt, const float* __restrict__ bias,
    u16* __restrict__ o0, u16* __restrict__ o1, u16* __restrict__ o2t){
  constexpr int K_ = 1024;
  __shared__ __align__(16) char smem[114688];  // [0,64K) A, [64K,112K) B
  int tid = threadIdx.x, w = tid >> 6, lane = tid & 63;
  int wm = w >> 1, wn = w & 1;
  int bid = blockIdx.y * gridDim.x + blockIdx.x;
  int nwg = gridDim.x * gridDim.y;           // 256
  int cpx = nwg >> 3;
  int swz = (bid & 7) * cpx + (bid >> 3);    // XCD-bijective
  int m0 = (swz / gridDim.x) * 256, n0 = (swz % gridDim.x) * 192;

  f32x4 z = {0.f, 0.f, 0.f, 0.f};
  f32x4 acc[4][6];
  #pragma unroll
  for(int r = 0; r < 4; r++)
    #pragma unroll
    for(int c = 0; c < 6; c++) acc[r][c] = z;

  int srow8 = tid >> 3;                      // 0..63
  int sch = (tid & 7) ^ (srow8 & 7);         // pre-swizzled source chunk
  auto STAGE_A = [&](int buf, int half, int kt){
    #pragma unroll
    for(int l = 0; l < 2; l++){
      int row = half*128 + l*64 + srow8;
      gl_lds16(A + (size_t)(m0 + row)*K_ + kt*64 + sch*8,
               smem + buf*32768 + half*16384 + l*8192 + tid*16);
    }
  };
  auto STAGE_B3 = [&](int slot, int third, int kt){
    int row = third*64 + srow8;
    gl_lds16(Bt + (size_t)(n0 + row)*K_ + kt*64 + sch*8,
             smem + 65536 + slot*24576 + third*8192 + tid*16);
  };

  int ln15 = lane & 15, g = lane >> 4;
  int co0 = ((g    ) ^ (ln15 & 7)) * 16;
  int co1 = ((4 + g) ^ (ln15 & 7)) * 16;
  auto LDA = [&](int buf, int r, int k)->short8{
    int row = wm*64 + r*16 + ln15;
    return *(const short8*)(smem + buf*32768 + row*128 + (k ? co1 : co0));
  };
  auto LDB = [&](int slot, int c, int k)->short8{
    int row = wn*96 + c*16 + ln15;
    return *(const short8*)(smem + 65536 + slot*24576 + row*128 + (k ? co1 : co0));
  };
  #define BAR()   __builtin_amdgcn_s_barrier()
  #define LGKM0() do{ asm volatile("s_waitcnt lgkmcnt(0)" ::: "memory"); \
                      __builtin_amdgcn_sched_barrier(0); }while(0)
  #define MF(r_, c_, a_, b_) acc[r_][c_] = __builtin_amdgcn_mfma_f32_16x16x32_bf16(a_, b_, acc[r_][c_], 0, 0, 0)

  constexpr int nk = K_ / 64;                // 16 K-tiles
  STAGE_A(0, 0, 0); STAGE_A(0, 1, 0);
  STAGE_B3(0, 0, 0); STAGE_B3(0, 1, 0); STAGE_B3(0, 2, 0);
  STAGE_B3(1, 0, 1); STAGE_B3(1, 1, 1); STAGE_B3(1, 2, 1);
  asm volatile("s_waitcnt vmcnt(3)" ::: "memory");
  __builtin_amdgcn_sched_barrier(0);
  BAR();

  #pragma unroll 2
  for(int t = 0; t < nk; t++){
    int buf = t & 1;
    int kA = (t + 1 < nk) ? t + 1 : nk - 1;
    int kB = (t + 2 < nk) ? t + 2 : nk - 1;
    short8 a[4][2], b01[2][2], b23[2][2], b45[2][2];
    // ---- P0: read a r0-3 + b c0-1 ; stage A(t+1,h0) ; mfma c0-1 ----
    #pragma unroll
    for(int r = 0; r < 4; r++){ a[r][0] = LDA(buf, r, 0); a[r][1] = LDA(buf, r, 1); }
    #pragma unroll
    for(int c = 0; c < 2; c++){ b01[c][0] = LDB(buf, c, 0); b01[c][1] = LDB(buf, c, 1); }
    STAGE_A(buf ^ 1, 0, kA);
    BAR(); LGKM0();
    __builtin_amdgcn_s_setprio(1);
    #pragma unroll
    for(int r = 0; r < 4; r++)
      #pragma unroll
      for(int c = 0; c < 2; c++){ MF(r, c, a[r][0], b01[c][0]); MF(r, c, a[r][1], b01[c][1]); }
    __builtin_amdgcn_s_setprio(0);
    BAR();
    // ---- P1: read b c2-3 ; stage A(t+1,h1) ; mfma c2-3 ----
    #pragma unroll
    for(int c = 0; c < 2; c++){ b23[c][0] = LDB(buf, c + 2, 0); b23[c][1] = LDB(buf, c + 2, 1); }
    STAGE_A(buf ^ 1, 1, kA);
    BAR(); LGKM0();
    __builtin_amdgcn_s_setprio(1);
    #pragma unroll
    for(int r = 0; r < 4; r++)
      #pragma unroll
      for(int c = 0; c < 2; c++){ MF(r, c+2, a[r][0], b23[c][0]); MF(r, c+2, a[r][1], b23[c][1]); }
    __builtin_amdgcn_s_setprio(0);
    BAR();
    // ---- P2: read b c4-5 ; mfma c4 ----
    #pragma unroll
    for(int c = 0; c < 2; c++){ b45[c][0] = LDB(buf, c + 4, 0); b45[c][1] = LDB(buf, c + 4, 1); }
    BAR(); LGKM0();
    __builtin_amdgcn_s_setprio(1);
    #pragma unroll
    for(int r = 0; r < 4; r++){ MF(r, 4, a[r][0], b45[0][0]); MF(r, 4, a[r][1], b45[0][1]); }
    __builtin_amdgcn_s_setprio(0);
    BAR();
    // ---- P3: stage B(t+2) x3 ; mfma c5 ; vmcnt(3) ----
    STAGE_B3(buf, 0, kB); STAGE_B3(buf, 1, kB); STAGE_B3(buf, 2, kB);
    BAR();
    __builtin_amdgcn_s_setprio(1);
    #pragma unroll
    for(int r = 0; r < 4; r++){ MF(r, 5, a[r][0], b45[1][0]); MF(r, 5, a[r][1], b45[1][1]); }
    __builtin_amdgcn_s_setprio(0);
    asm volatile("s_waitcnt vmcnt(3)" ::: "memory");   // K-tile t+1 resident
    __builtin_amdgcn_sched_barrier(0);
    BAR();
  }
  #undef BAR
  #undef LGKM0
  #undef MF

  // ---- epilogue: Q x0.125*log2e, K -> [BH][S][HD]; V -> Vt [BH][HD][S] ----
  int h = n0 / 192;
  #pragma unroll
  for(int r = 0; r < 4; r++){
    #pragma unroll
    for(int c = 0; c < 6; c++){
      #pragma unroll
      for(int q = 0; q < 4; q++){
        int row = m0 + wm*64 + r*16 + g*4 + q;
        int rr = wn*96 + c*16 + ln15;
        float v = acc[r][c][q] + bias[h*192 + rr];
        int b = row >> 11, s = row & (S_ - 1);
        if(rr < 64){
          o0[((size_t)(b*H_ + h)*S_ + s)*HD_ + rr] = f2b(v * 0.180336884f);  // 0.125*log2(e)
        } else if(rr < 128){
          o1[((size_t)(b*H_ + h)*S_ + s)*HD_ + rr - 64] = f2b(v);
        } else {
          o2t[((size_t)(b*H_ + h)*HD_ + rr - 128)*S_ + s] = f2b(v);          // transposed
        }
      }
    }
  }
}

// ------- GEMM2, 8-wave, SINGLE-barrier 2-phase pipeline, XCD swizzle -------
__global__ __launch_bounds__(512) void gemm_kernel(const u16* __restrict__ A,
    const u16* __restrict__ Bt, const float* __restrict__ bias,
    float* __restrict__ out, int K, int N){
  __shared__ u16 As[2][128*32];
  __shared__ u16 Bs[2][128*32];
  int tid = threadIdx.x, w = tid >> 6, lane = tid & 63;
  int ln15 = lane & 15, g = lane >> 4;
  int bid = blockIdx.y * gridDim.x + blockIdx.x;
  int nwg = gridDim.x * gridDim.y;
  int cpx = nwg >> 3;
  int swz = (bid & 7) * cpx + (bid >> 3);
  int m0 = (swz / gridDim.x) * 128, n0 = (swz % gridDim.x) * 128;
  int wm = w >> 2, wn = w & 3;
  f32x4 z = {0.f, 0.f, 0.f, 0.f};
  f32x4 acc[4][2];
  #pragma unroll
  for(int r = 0; r < 4; r++){ acc[r][0] = z; acc[r][1] = z; }
  int srow = tid >> 2, sch = (tid & 3) * 8;        // 512 thr cover 128x32 in one shot
  const u16* Ag = A + (size_t)(m0 + srow) * K + sch;
  const u16* Bg = Bt + (size_t)(n0 + srow) * K + sch;

  auto STAGE = [&](int buf, int kt){
    gl_lds16(Ag + kt, &As[buf][srow*32 + sch]);
    gl_lds16(Bg + kt, &Bs[buf][srow*32 + sch]);
  };

  int nk = K >> 5;
  STAGE(0, 0);
  int cur = 0;
  for(int t = 0; t < nk; t++){
    asm volatile("s_waitcnt vmcnt(0)" ::: "memory");   // own stage(t) pair landed
    __builtin_amdgcn_sched_barrier(0);
    __builtin_amdgcn_s_barrier();                      // all waves' t-loads landed
                                                       // + all finished compute t-1
    if(t + 1 < nk) STAGE(cur ^ 1, (t + 1) * 32);       // overwrite-safe post-barrier
    int kc = g * 8;
    int ar = wm*64 + ln15;
    int bc = wn*32 + ln15;
    short8 af[4], bfr[2];
    #pragma unroll
    for(int r = 0; r < 4; r++) af[r] = *(const short8*)&As[cur][(ar + r*16)*32 + kc];
    #pragma unroll
    for(int c = 0; c < 2; c++) bfr[c] = *(const short8*)&Bs[cur][(bc + c*16)*32 + kc];
    __builtin_amdgcn_s_setprio(1);
    #pragma unroll
    for(int r = 0; r < 4; r++)
      #pragma unroll
      for(int c = 0; c < 2; c++)
        acc[r][c] = __builtin_amdgcn_mfma_f32_16x16x32_bf16(af[r], bfr[c], acc[r][c], 0, 0, 0);
    __builtin_amdgcn_s_setprio(0);
    cur ^= 1;
  }

  #pragma unroll
  for(int r = 0; r < 4; r++){
    #pragma unroll
    for(int c = 0; c < 2; c++){
      #pragma unroll
      for(int q = 0; q < 4; q++){
        int row = m0 + wm*64 + r*16 + g*4 + q;
        int col = n0 + wn*32 + c*16 + ln15;
        out[(size_t)row * N + col] = acc[r][c][q] + bias[col];
      }
    }
  }
}

// ======================= causal flash attention =======================
// 1024 blocks: one q-strip per block, 8 waves; waves 0-3 kv-half0, 4-7
// kv-half1; shared P; deferred l; R15 big-first decode; bh->XCD grouping.
// Single-barrier pipeline; explicit sync before merge (Mg overlaps K/V).

template<int HALF>  // 0 = kv 0..31, 1 = kv 32..63
__device__ __forceinline__ void compute_tile(
    const char* KsB, const char* VsB, char* Pw, const short8* qf,
    f32x4* o, float& m_run, float& l_run, bool diag, int lane, int wr){
  constexpr int KB0 = (HALF == 1) ? 2 : 0;
  f32x4 z = {0.f, 0.f, 0.f, 0.f};
  f32x4 sf[4];
  __builtin_amdgcn_s_setprio(1);
  #pragma unroll
  for(int kb = KB0; kb < KB0 + 2; kb++){
    f32x4 acc = z;
    #pragma unroll
    for(int c = 0; c < 2; c++){
      int row = kb*16 + (lane & 15);
      int kc16 = (lane >> 4) + c*4;
      short8 kf = *(const short8*)(KsB + row*128 + ((kc16 ^ (row & 7)) * 16));
      acc = __builtin_amdgcn_mfma_f32_16x16x32_bf16(kf, qf[c], acc, 0, 0, 0);
    }
    sf[kb] = acc;
  }
  __builtin_amdgcn_s_setprio(0);
  if(diag){
    int qo = wr*16 + (lane & 15);
    #pragma unroll
    for(int kb = KB0; kb < KB0 + 2; kb++)
      #pragma unroll
      for(int r = 0; r < 4; r++){
        int kvo = kb*16 + (lane >> 4)*4 + r;
        if(kvo > qo) sf[kb][r] = -1e30f;
      }
  }
  int g = lane >> 4;
  float pmax = -1e28f;                       // floor: fully-masked rows -> p=0
  #pragma unroll
  for(int kb = KB0; kb < KB0 + 2; kb++)
    pmax = fmaxf(pmax, fmaxf(fmaxf(sf[kb][0], sf[kb][1]), fmaxf(sf[kb][2], sf[kb][3])));
  pmax = fmaxf(pmax, __shfl_xor(pmax, 16));
  pmax = fmaxf(pmax, __shfl_xor(pmax, 32));
  if(!__all(pmax <= m_run + 8.f)){           // T13 defer-max (log2 domain)
    float mn = fmaxf(m_run, pmax);
    float al = exp2v(m_run - mn);
    m_run = mn;
    l_run *= al;                             // per-lane partial (deferred reduce)
    float alr[4];
    #pragma unroll
    for(int r = 0; r < 4; r++) alr[r] = __shfl(al, g*4 + r);
    #pragma unroll
    for(int n = 0; n < 4; n++)
      #pragma unroll
      for(int r = 0; r < 4; r++) o[n][r] *= alr[r];
  }
  float p[4][4];
  float sum = 0.f;
  #pragma unroll
  for(int kb = KB0; kb < KB0 + 2; kb++){
    #pragma unroll
    for(int r = 0; r < 4; r++) p[kb][r] = exp2v(sf[kb][r] - m_run);
    sum += (p[kb][0]+p[kb][1]) + (p[kb][2]+p[kb][3]);
  }
  l_run += sum;                              // no per-tile cross-lane reduce
  int qrow = lane & 15;
  #pragma unroll
  for(int kb = KB0; kb < KB0 + 2; kb++){
    u32 lo, hi;
    asm("v_cvt_pk_bf16_f32 %0, %1, %2" : "=v"(lo) : "v"(p[kb][0]), "v"(p[kb][1]));
    asm("v_cvt_pk_bf16_f32 %0, %1, %2" : "=v"(hi) : "v"(p[kb][2]), "v"(p[kb][3]));
    uint2 pk; pk.x = lo; pk.y = hi;
    int byt = (qrow*128 + kb*32 + g*8) ^ ((qrow & 7) << 4);
    *(uint2*)(Pw + byt) = pk;
  }
  __builtin_amdgcn_s_setprio(1);
  {
    constexpr int c = HALF;
    int prow = lane & 15;
    int kb16 = ((lane >> 4) + c*4) * 16;
    short8 pa = *(const short8*)(Pw + ((prow*128 + kb16) ^ ((prow & 7) << 4)));
    #pragma unroll
    for(int n = 0; n < 4; n++){
      int vrow = n*16 + (lane & 15);
      int kc16 = (lane >> 4) + c*4;
      short8 vf = *(const short8*)(VsB + vrow*128 + ((kc16 ^ (vrow & 7)) * 16));
      o[n] = __builtin_amdgcn_mfma_f32_16x16x32_bf16(pa, vf, o[n], 0, 0, 0);
    }
  }
  __builtin_amdgcn_s_setprio(0);
}

__global__ __launch_bounds__(512) void attn_kernel(const u16* __restrict__ Q,
    const u16* __restrict__ Kb, const u16* __restrict__ Vt, u16* __restrict__ O){
  // LDS: [0,32K) K/V dbuf | [32K,40K) P (4 regions x 2KB, shared by role pairs)
  __shared__ __align__(16) char smem[40960];
  char* PsBase = smem + 32768;
  int tid = threadIdx.x, w = tid >> 6, lane = tid & 63;
  int wr = w & 3, role = w >> 2;
  // R15 big-first decode: qt descends with L; L%8 = bh&7 keeps XCD L2 grouping
  int L = blockIdx.x;
  int qt = 31 - (L >> 5);
  int bh = (L & 7) + 8 * ((L >> 3) & 3);
  const u16* Qg = Q + (size_t)bh * S_ * HD_;
  const u16* Kg = Kb + (size_t)bh * S_ * HD_;
  const u16* Vg = Vt + (size_t)bh * HD_ * S_;
  int b = bh >> 4, h = bh & 15;

  short8 qf[2];
  {
    int rq = qt*64 + wr*16 + (lane & 15);
    #pragma unroll
    for(int c = 0; c < 2; c++)
      qf[c] = *(const short8*)(Qg + (size_t)rq*HD_ + (lane >> 4)*8 + c*32);
  }
  f32x4 z = {0.f, 0.f, 0.f, 0.f};
  f32x4 o[4];
  float m_run = -1e30f, l_run = 0.f;
  #pragma unroll
  for(int i = 0; i < 4; i++) o[i] = z;
  int svrow = lane >> 3, scb = lane & 7;

  auto STAGE = [&](int buf, int kt){
    int kv0 = kt * 64;
    int rowblk = w * 8;
    int row = rowblk + svrow;
    int cbs = scb ^ (row & 7);
    gl_lds16(Kg + (size_t)(kv0 + row)*HD_ + cbs*8, smem + buf*8192 + rowblk*128);
    gl_lds16(Vg + (size_t)row*S_ + kv0 + cbs*8, smem + 16384 + buf*8192 + rowblk*128);
  };

  STAGE(0, 0);
  int cur = 0;
  char* Pw = PsBase + wr*2048;         // shared by role pair (disjoint XOR byte sets)
  for(int kt = 0; kt <= qt; kt++){
    asm volatile("s_waitcnt vmcnt(0)" ::: "memory");   // own stage(kt) pair landed
    __builtin_amdgcn_sched_barrier(0);
    __builtin_amdgcn_s_barrier();                      // all kt-loads landed + all
                                                       // finished compute kt-1
    if(kt < qt) STAGE(cur ^ 1, kt + 1);                // overwrite-safe post-barrier
    const char* KsB = (const char*)(smem + cur*8192);
    const char* VsB = (const char*)(smem + 16384 + cur*8192);
    if(role == 0) compute_tile<0>(KsB, VsB, Pw, qf, o, m_run, l_run, kt == qt, lane, wr);
    else          compute_tile<1>(KsB, VsB, Pw, qf, o, m_run, l_run, kt == qt, lane, wr);
    cur ^= 1;
  }

  // reduce deferred per-lane l once per sweep
  l_run += __shfl_xor(l_run, 16);
  l_run += __shfl_xor(l_run, 32);

  __syncthreads();   // ALL waves done with K/V LDS before Mg (overlapping) is written

  // merge half0 (role0) x half1 (role1): role1 publishes, role0 merges+writes
  float* Mg = (float*)smem + wr*1072;
  if(role == 1){
    #pragma unroll
    for(int n = 0; n < 4; n++)
      #pragma unroll
      for(int r = 0; r < 4; r++)
        Mg[((lane >> 4)*4 + r)*65 + n*16 + (lane & 15)] = o[n][r];
    if(lane < 16){ Mg[1040 + lane] = m_run; Mg[1056 + lane] = l_run; }
  }
  __syncthreads();
  if(role == 0){
    float F1[4], F2[4], den[4];
    #pragma unroll
    for(int r = 0; r < 4; r++){
      int row = (lane >> 4)*4 + r;
      float m1r = __shfl(m_run, row);
      float l1r = __shfl(l_run, row);
      float m2r = Mg[1040 + row];
      float l2r = Mg[1056 + row];
      float mm = fmaxf(m1r, m2r);
      F1[r] = exp2v(m1r - mm);
      F2[r] = exp2v(m2r - mm);
      den[r] = 1.f / (l1r*F1[r] + l2r*F2[r]);
    }
    #pragma unroll
    for(int n = 0; n < 4; n++)
      #pragma unroll
      for(int r = 0; r < 4; r++){
        int row = (lane >> 4)*4 + r;
        float o2 = Mg[row*65 + n*16 + (lane & 15)];
        float val = (o[n][r]*F1[r] + o2*F2[r]) * den[r];
        int s = qt*64 + wr*16 + row;
        int hd = n*16 + (lane & 15);
        O[(((size_t)(b*S_ + s))*H_ + h)*HD_ + hd] = f2b(val);
      }
  }
}

extern "C" void kernel_launch(void* const* d_in, const int* in_sizes, int n_in,
                              void* d_out, int out_size, void* d_ws, size_t ws_size,
                              hipStream_t stream){
  (void)in_sizes; (void)n_in; (void)out_size; (void)ws_size;
  const float* x    = (const float*)d_in[0];
  const float* gam  = (const float*)d_in[1];
  const float* bet  = (const float*)d_in[2];
  const float* wqkv = (const float*)d_in[3];
  const float* bqkv = (const float*)d_in[4];
  const float* wout = (const float*)d_in[5];
  const float* bout = (const float*)d_in[6];
  char* ws = (char*)d_ws;
  u16* xn    = (u16*)(ws);
  u16* wqkvT = (u16*)(ws + 8388608);
  u16* woutT = (u16*)(ws + 8388608 + 6291456);
  u16* Qb    = (u16*)(ws + 16777216);
  u16* Kb    = (u16*)(ws + 16777216 + 8388608);
  u16* Vt    = (u16*)(ws + 16777216 + 2*8388608);
  u16* attnb = xn;                      // xn dead after GEMM1 -> reuse
  float* out = (float*)d_out;           // f32 output

  prep_kernel<<<dim3(M_ + (NQKV_/64)*(D_/64) + (D_/64)*(D_/64)), dim3(256), 0, stream>>>(
      x, gam, bet, xn, wqkv, wqkvT, wout, woutT);
  gemm256_kernel<<<dim3(NQKV_/192, M_/256), dim3(512), 0, stream>>>(xn, wqkvT, bqkv, Qb, Kb, Vt);
  attn_kernel<<<dim3(32*B_*H_), dim3(512), 0, stream>>>(Qb, Kb, Vt, attnb);
  gemm_kernel<<<dim3(D_/128, M_/128), dim3(512), 0, stream>>>(attnb, woutT, bout, out, D_, D_);
}